// Round 1
// baseline (3463.894 us; speedup 1.0000x reference)
//
#include <hip/hip_runtime.h>
#include <math.h>

#define BATCH 2
#define SEQLEN 2048
#define DMODEL 1024
#define NHEADS 16
#define DKH 64
#define TOPK 1024
#define MROWS (BATCH * SEQLEN)  // 4096

// ---------------- GEMM: C[M,N] = A[M,K] @ W[N,K]^T + bias[N] ----------------
__global__ __launch_bounds__(256) void gemm_xwT(
    const float* __restrict__ A, const float* __restrict__ W,
    const float* __restrict__ bias, float* __restrict__ C,
    int M, int N, int K) {
  constexpr int BM = 128, BN = 128, BK = 16, PAD = 4;
  __shared__ float As[BK][BM + PAD];
  __shared__ float Bs[BK][BN + PAD];
  const int t = threadIdx.x;
  const int bm = blockIdx.y * BM, bn = blockIdx.x * BN;
  const int tn = t & 15, tm = t >> 4;
  float acc[8][8] = {};
  for (int k0 = 0; k0 < K; k0 += BK) {
#pragma unroll
    for (int i = 0; i < 2; ++i) {
      int i4 = t * 2 + i;
      int m = i4 >> 2, kv = (i4 & 3) * 4;
      float4 a = *(const float4*)&A[(size_t)(bm + m) * K + k0 + kv];
      As[kv + 0][m] = a.x; As[kv + 1][m] = a.y;
      As[kv + 2][m] = a.z; As[kv + 3][m] = a.w;
      float4 b = *(const float4*)&W[(size_t)(bn + m) * K + k0 + kv];
      Bs[kv + 0][m] = b.x; Bs[kv + 1][m] = b.y;
      Bs[kv + 2][m] = b.z; Bs[kv + 3][m] = b.w;
    }
    __syncthreads();
#pragma unroll
    for (int kk = 0; kk < BK; ++kk) {
      float ar[8], br[8];
      *(float4*)&ar[0] = *(const float4*)&As[kk][tm * 8];
      *(float4*)&ar[4] = *(const float4*)&As[kk][tm * 8 + 4];
      *(float4*)&br[0] = *(const float4*)&Bs[kk][tn * 8];
      *(float4*)&br[4] = *(const float4*)&Bs[kk][tn * 8 + 4];
#pragma unroll
      for (int i = 0; i < 8; ++i)
#pragma unroll
        for (int j = 0; j < 8; ++j)
          acc[i][j] = fmaf(ar[i], br[j], acc[i][j]);
    }
    __syncthreads();
  }
#pragma unroll
  for (int i = 0; i < 8; ++i) {
    int row = bm + tm * 8 + i;
#pragma unroll
    for (int jv = 0; jv < 2; ++jv) {
      int col = bn + tn * 8 + jv * 4;
      float4 o;
      o.x = acc[i][jv * 4 + 0] + bias[col + 0];
      o.y = acc[i][jv * 4 + 1] + bias[col + 1];
      o.z = acc[i][jv * 4 + 2] + bias[col + 2];
      o.w = acc[i][jv * 4 + 3] + bias[col + 3];
      *(float4*)&C[(size_t)row * N + col] = o;
    }
  }
}

// ---------------- wave(64) reductions ----------------
__device__ __forceinline__ int wred_isum(int v) {
#pragma unroll
  for (int o = 32; o > 0; o >>= 1) v += __shfl_xor(v, o);
  return v;
}
__device__ __forceinline__ float wred_fsum(float v) {
#pragma unroll
  for (int o = 32; o > 0; o >>= 1) v += __shfl_xor(v, o);
  return v;
}
__device__ __forceinline__ float wred_fmax(float v) {
#pragma unroll
  for (int o = 32; o > 0; o >>= 1) v = fmaxf(v, __shfl_xor(v, o));
  return v;
}

// ---------------- fused prob-sparse attention ----------------
// grid: B*H*(SEQLEN/16) blocks of 256 threads (4 waves).
// Per block: q-tile of 16 rows for one (b,h). Scores [16][2048] in LDS.
// Exact top-1024 threshold per row via bisection on monotone u32 keys.
__global__ __launch_bounds__(256) void attn_topk(
    const float* __restrict__ Qp, const float* __restrict__ Kp,
    const float* __restrict__ Vp, float* __restrict__ Ctx) {
  __shared__ float sc[16][SEQLEN];   // 128 KiB
  __shared__ float qs[16][DKH];      // 4 KiB
  __shared__ float4 red4[4][256];    // 16 KiB
  __shared__ float rinvZ[16];

  const int wg = blockIdx.x;
  const int bh = wg >> 7;            // 128 q-tiles per (b,h)
  const int qt = wg & 127;
  const int b = bh >> 4, h = bh & 15;
  const int q0 = qt * 16;
  const int t = threadIdx.x;
  const int w = t >> 6, lane = t & 63;

  // ---- load Q tile: 16 x 64 floats ----
  {
    int row = t >> 4, c4 = (t & 15) * 4;
    *(float4*)&qs[row][c4] =
        *(const float4*)&Qp[((size_t)(b * SEQLEN + q0 + row)) * DMODEL + h * DKH + c4];
  }
  __syncthreads();

  const size_t kvbase = (size_t)b * SEQLEN * DMODEL + (size_t)h * DKH;

  // ---- QK^T: wave w owns k in [w*512, w*512+512) ----
#pragma unroll 1
  for (int i = 0; i < 8; ++i) {
    int k = w * 512 + i * 64 + lane;
    const float* kp = &Kp[kvbase + (size_t)k * DMODEL];
    float4 kr[16];
#pragma unroll
    for (int dv = 0; dv < 16; ++dv) kr[dv] = *(const float4*)&kp[dv * 4];
#pragma unroll 2
    for (int q = 0; q < 16; ++q) {
      float a0 = 0.f, a1 = 0.f, a2 = 0.f, a3 = 0.f;
#pragma unroll
      for (int dv = 0; dv < 16; ++dv) {
        float4 qv = *(const float4*)&qs[q][dv * 4];
        a0 = fmaf(qv.x, kr[dv].x, a0);
        a1 = fmaf(qv.y, kr[dv].y, a1);
        a2 = fmaf(qv.z, kr[dv].z, a2);
        a3 = fmaf(qv.w, kr[dv].w, a3);
      }
      sc[q][k] = ((a0 + a1) + (a2 + a3)) * 0.125f;
    }
  }
  __syncthreads();

  // ---- exact top-1024 threshold + softmax numerators (wave w -> rows 4w..4w+3) ----
#pragma unroll 1
  for (int j = 0; j < 4; ++j) {
    const int q = w * 4 + j;
    float vmax = -3.4e38f;
    unsigned key[32];
#pragma unroll
    for (int ii = 0; ii < 32; ++ii) {
      float s = sc[q][lane + 64 * ii];
      vmax = fmaxf(vmax, s);
      unsigned u = __float_as_uint(s);
      key[ii] = (u & 0x80000000u) ? ~u : (u | 0x80000000u);
    }
    vmax = wred_fmax(vmax);
    unsigned maxk;
    { unsigned u = __float_as_uint(vmax); maxk = (u & 0x80000000u) ? ~u : (u | 0x80000000u); }
    // binary search: largest T with count(key >= T) >= TOPK  (== kth-largest key)
    unsigned lo = 0u, hi = maxk + 1u;
    while (hi - lo > 1u) {
      unsigned mid = lo + ((hi - lo) >> 1);
      int c = 0;
#pragma unroll
      for (int ii = 0; ii < 32; ++ii) c += (key[ii] >= mid) ? 1 : 0;
      c = wred_isum(c);
      if (c >= TOPK) lo = mid; else hi = mid;
    }
    const unsigned T = lo;
    float zp = 0.f;
#pragma unroll
    for (int ii = 0; ii < 32; ++ii) {
      float e = 0.f;
      if (key[ii] >= T) {
        unsigned u = (key[ii] & 0x80000000u) ? (key[ii] & 0x7fffffffu) : ~key[ii];
        e = expf(__uint_as_float(u) - vmax);
      }
      sc[q][lane + 64 * ii] = e;
      zp += e;
    }
    float Z = wred_fsum(zp);
    if (lane == 0) rinvZ[q] = 1.f / Z;
  }
  __syncthreads();

  // ---- PV: wave w owns k in [w*512, w*512+512), covers all (q,d) ----
  {
    const int dv = lane & 15;   // d = dv*4
    const int qg = lane >> 4;   // q = qg*4 + i
    float4 acc[4];
#pragma unroll
    for (int i = 0; i < 4; ++i) acc[i] = make_float4(0.f, 0.f, 0.f, 0.f);
    for (int k = w * 512; k < w * 512 + 512; ++k) {
      float4 v4 = *(const float4*)&Vp[kvbase + (size_t)k * DMODEL + dv * 4];
#pragma unroll
      for (int i = 0; i < 4; ++i) {
        float p = sc[qg * 4 + i][k];
        acc[i].x = fmaf(p, v4.x, acc[i].x);
        acc[i].y = fmaf(p, v4.y, acc[i].y);
        acc[i].z = fmaf(p, v4.z, acc[i].z);
        acc[i].w = fmaf(p, v4.w, acc[i].w);
      }
    }
#pragma unroll
    for (int i = 0; i < 4; ++i) red4[w][(qg * 4 + i) * 16 + dv] = acc[i];
  }
  __syncthreads();

  // ---- cross-wave reduce, scale by 1/Z, store ctx in [B*L, D] layout ----
  {
    int q = t >> 4, dv = t & 15;
    float4 p0 = red4[0][t], p1 = red4[1][t], p2 = red4[2][t], p3 = red4[3][t];
    float s = rinvZ[q];
    float4 o;
    o.x = (p0.x + p1.x + p2.x + p3.x) * s;
    o.y = (p0.y + p1.y + p2.y + p3.y) * s;
    o.z = (p0.z + p1.z + p2.z + p3.z) * s;
    o.w = (p0.w + p1.w + p2.w + p3.w) * s;
    *(float4*)&Ctx[((size_t)(b * SEQLEN + q0 + q)) * DMODEL + h * DKH + dv * 4] = o;
  }
}

extern "C" void kernel_launch(void* const* d_in, const int* in_sizes, int n_in,
                              void* d_out, int out_size, void* d_ws, size_t ws_size,
                              hipStream_t stream) {
  const float* q  = (const float*)d_in[0];
  const float* k  = (const float*)d_in[1];
  const float* v  = (const float*)d_in[2];
  const float* Wq = (const float*)d_in[3];
  const float* bq = (const float*)d_in[4];
  const float* Wk = (const float*)d_in[5];
  const float* bk = (const float*)d_in[6];
  const float* Wv = (const float*)d_in[7];
  const float* bv = (const float*)d_in[8];
  const float* Wo = (const float*)d_in[9];
  const float* bo = (const float*)d_in[10];
  float* out = (float*)d_out;
  float* ws = (float*)d_ws;

  const size_t slab = (size_t)MROWS * DMODEL;  // 4 Mi floats = 16 MiB
  float* Qp = ws;
  float* Kp = ws + slab;
  float* Vp = ws + 2 * slab;
  // ctx reuses the Qp slab: each workgroup reads its Q tile (then syncs)
  // before writing the exact same elements as ctx -> element-exclusive, race-free.
  float* Ctx = Qp;

  dim3 gg(DMODEL / 128, MROWS / 128);
  gemm_xwT<<<gg, 256, 0, stream>>>(q, Wq, bq, Qp, MROWS, DMODEL, DMODEL);
  gemm_xwT<<<gg, 256, 0, stream>>>(k, Wk, bk, Kp, MROWS, DMODEL, DMODEL);
  gemm_xwT<<<gg, 256, 0, stream>>>(v, Wv, bv, Vp, MROWS, DMODEL, DMODEL);
  attn_topk<<<BATCH * NHEADS * (SEQLEN / 16), 256, 0, stream>>>(Qp, Kp, Vp, Ctx);
  gemm_xwT<<<gg, 256, 0, stream>>>(Ctx, Wo, bo, out, MROWS, DMODEL, DMODEL);
}

// Round 2
// 1325.489 us; speedup vs baseline: 2.6133x; 2.6133x over previous
//
#include <hip/hip_runtime.h>
#include <math.h>

#define BATCH 2
#define SEQ 2048
#define DM 1024
#define NH 16
#define DH 64
#define TOPKN 1024
#define MROWS (BATCH * SEQ)  // 4096

typedef float f32x4 __attribute__((ext_vector_type(4)));
typedef short s16x8 __attribute__((ext_vector_type(8)));

__device__ __forceinline__ unsigned short f2bf(float x) {
  unsigned u = __float_as_uint(x);
  return (unsigned short)((u + 0x7FFFu + ((u >> 16) & 1u)) >> 16);
}
__device__ __forceinline__ unsigned packHL(float x) {
  unsigned h = f2bf(x);
  float r = x - __uint_as_float(h << 16);
  unsigned l = f2bf(r);
  return h | (l << 16);
}

// ---------------- GEMM: C[M,N] = A[M,K] @ W[N,K]^T + bias[N] ----------------
// MODE 0: f32 out.  MODE 1: packed (hi|lo<<16) u32, value*0.125 (Q).
// MODE 2: two bf16 slabs hi/lo (K).  MODE 3: bf16 transposed [B][H][DH][SEQ] (V).
template <int MODE>
__global__ __launch_bounds__(256) void gemm_xwT(
    const float* __restrict__ A, const float* __restrict__ W,
    const float* __restrict__ bias, void* __restrict__ out0,
    void* __restrict__ out1, int M, int N, int K) {
  constexpr int BM = 128, BN = 128, BK = 16, PAD = 4;
  __shared__ float As[BK][BM + PAD];
  __shared__ float Bs[BK][BN + PAD];
  const int t = threadIdx.x;
  const int bm = blockIdx.y * BM, bn = blockIdx.x * BN;
  const int tn = t & 15, tm = t >> 4;
  float acc[8][8] = {};
  for (int k0 = 0; k0 < K; k0 += BK) {
#pragma unroll
    for (int i = 0; i < 2; ++i) {
      int i4 = t * 2 + i;
      int m = i4 >> 2, kv = (i4 & 3) * 4;
      float4 a = *(const float4*)&A[(size_t)(bm + m) * K + k0 + kv];
      As[kv + 0][m] = a.x; As[kv + 1][m] = a.y;
      As[kv + 2][m] = a.z; As[kv + 3][m] = a.w;
      float4 b = *(const float4*)&W[(size_t)(bn + m) * K + k0 + kv];
      Bs[kv + 0][m] = b.x; Bs[kv + 1][m] = b.y;
      Bs[kv + 2][m] = b.z; Bs[kv + 3][m] = b.w;
    }
    __syncthreads();
#pragma unroll
    for (int kk = 0; kk < BK; ++kk) {
      float ar[8], br[8];
      *(float4*)&ar[0] = *(const float4*)&As[kk][tm * 8];
      *(float4*)&ar[4] = *(const float4*)&As[kk][tm * 8 + 4];
      *(float4*)&br[0] = *(const float4*)&Bs[kk][tn * 8];
      *(float4*)&br[4] = *(const float4*)&Bs[kk][tn * 8 + 4];
#pragma unroll
      for (int i = 0; i < 8; ++i)
#pragma unroll
        for (int j = 0; j < 8; ++j)
          acc[i][j] = fmaf(ar[i], br[j], acc[i][j]);
    }
    __syncthreads();
  }

  if (MODE == 0) {
    float* C = (float*)out0;
#pragma unroll
    for (int i = 0; i < 8; ++i) {
      int row = bm + tm * 8 + i;
#pragma unroll
      for (int jv = 0; jv < 2; ++jv) {
        int col = bn + tn * 8 + jv * 4;
        float4 o;
        o.x = acc[i][jv * 4 + 0] + bias[col + 0];
        o.y = acc[i][jv * 4 + 1] + bias[col + 1];
        o.z = acc[i][jv * 4 + 2] + bias[col + 2];
        o.w = acc[i][jv * 4 + 3] + bias[col + 3];
        *(float4*)&C[(size_t)row * N + col] = o;
      }
    }
  } else if (MODE == 1) {
    unsigned* Q = (unsigned*)out0;
#pragma unroll
    for (int i = 0; i < 8; ++i) {
      int row = bm + tm * 8 + i;
      unsigned wds[8];
#pragma unroll
      for (int j = 0; j < 8; ++j)
        wds[j] = packHL((acc[i][j] + bias[bn + tn * 8 + j]) * 0.125f);
      *(uint4*)&Q[(size_t)row * N + bn + tn * 8] = *(uint4*)&wds[0];
      *(uint4*)&Q[(size_t)row * N + bn + tn * 8 + 4] = *(uint4*)&wds[4];
    }
  } else if (MODE == 2) {
    unsigned short* Khi = (unsigned short*)out0;
    unsigned short* Klo = (unsigned short*)out1;
#pragma unroll
    for (int i = 0; i < 8; ++i) {
      int row = bm + tm * 8 + i;
      union { s16x8 v; unsigned short s[8]; } hi_, lo_;
#pragma unroll
      for (int j = 0; j < 8; ++j) {
        float x = acc[i][j] + bias[bn + tn * 8 + j];
        unsigned short hb = f2bf(x);
        hi_.s[j] = hb;
        lo_.s[j] = f2bf(x - __uint_as_float((unsigned)hb << 16));
      }
      *(s16x8*)&Khi[(size_t)row * N + bn + tn * 8] = hi_.v;
      *(s16x8*)&Klo[(size_t)row * N + bn + tn * 8] = lo_.v;
    }
  } else {  // MODE 3: Vt[b][h][dh][l]
    unsigned short* Vt = (unsigned short*)out0;
    int brow = bm >> 11;
    int l0 = (bm & (SEQ - 1)) + tm * 8;
#pragma unroll
    for (int j = 0; j < 8; ++j) {
      int dcol = bn + tn * 8 + j;
      int h = dcol >> 6, dh = dcol & 63;
      union { s16x8 v; unsigned short s[8]; } vv;
#pragma unroll
      for (int i = 0; i < 8; ++i) vv.s[i] = f2bf(acc[i][j] + bias[dcol]);
      *(s16x8*)&Vt[(((size_t)brow * NH + h) * DH + dh) * SEQ + l0] = vv.v;
    }
  }
}

// ---------------- fused prob-sparse attention (MFMA) ----------------
// 4096 WGs x 256 thr (4 waves). WG = one (b,h) x 16-row q-tile.
// Wave w: QK^T over k-slice [w*512,(w+1)*512) -> 32 f32x4 acc frags (regs).
// Exact top-1024 threshold: 32-round bisection on u32 keys, compares in f32
// on register scores, cross-wave counts via LDS. P (bf16) staged in LDS,
// PV via MFMA with wave-private d-slice of 16.
__global__ __launch_bounds__(256, 2) void attn_mfma(
    const unsigned* __restrict__ QHL, const unsigned short* __restrict__ Khi,
    const unsigned short* __restrict__ Klo, const unsigned short* __restrict__ Vt,
    float* __restrict__ Ctx) {
  __shared__ unsigned short P[16][2056];          // 65792 B, pad 8 bf16
  __shared__ __align__(16) float vz[16][4];       // vmax partials, then Z partials
  __shared__ __align__(16) int cntp[16][4];

  int wg = blockIdx.x;
  wg = (wg & 7) * 512 + (wg >> 3);                // XCD-contiguous (b,h) groups
  const int bh = wg >> 7, qt = wg & 127;
  const int b = bh >> 4, h = bh & 15;
  const int q0 = qt * 16;
  const int t = threadIdx.x, w = t >> 6, lane = t & 63;
  const int g = lane >> 4, c = lane & 15;
  const size_t rowb = (size_t)b * SEQ;

  // ---- Q fragments (packed u32, pre-scaled by 1/8) ----
  s16x8 qhi[2], qlo[2];
  {
    const unsigned* qp = QHL + (rowb + q0 + c) * DM + h * DH + g * 8;
#pragma unroll
    for (int ds = 0; ds < 2; ++ds) {
      unsigned uw[8];
      *(uint4*)&uw[0] = *(const uint4*)(qp + ds * 32);
      *(uint4*)&uw[4] = *(const uint4*)(qp + ds * 32 + 4);
      union { s16x8 v; unsigned u[4]; } hi_, lo_;
#pragma unroll
      for (int p = 0; p < 4; ++p) {
        hi_.u[p] = (uw[2 * p] & 0xFFFFu) | (uw[2 * p + 1] << 16);
        lo_.u[p] = (uw[2 * p] >> 16) | (uw[2 * p + 1] & 0xFFFF0000u);
      }
      qhi[ds] = hi_.v; qlo[ds] = lo_.v;
    }
  }

  // ---- QK^T: S = Qhi*Khi + Qhi*Klo + Qlo*Khi ----
  f32x4 accs[32];
#pragma unroll
  for (int i = 0; i < 32; ++i) accs[i] = (f32x4){0.f, 0.f, 0.f, 0.f};
  {
    const size_t kcol = (size_t)h * DH + g * 8;
#pragma unroll
    for (int tt = 0; tt < 32; ++tt) {
      const size_t krow = (rowb + w * 512 + tt * 16 + c) * DM + kcol;
      s16x8 kh0 = *(const s16x8*)(Khi + krow);
      s16x8 kh1 = *(const s16x8*)(Khi + krow + 32);
      s16x8 kl0 = *(const s16x8*)(Klo + krow);
      s16x8 kl1 = *(const s16x8*)(Klo + krow + 32);
      accs[tt] = __builtin_amdgcn_mfma_f32_16x16x32_bf16(qhi[0], kh0, accs[tt], 0, 0, 0);
      accs[tt] = __builtin_amdgcn_mfma_f32_16x16x32_bf16(qhi[1], kh1, accs[tt], 0, 0, 0);
      accs[tt] = __builtin_amdgcn_mfma_f32_16x16x32_bf16(qhi[0], kl0, accs[tt], 0, 0, 0);
      accs[tt] = __builtin_amdgcn_mfma_f32_16x16x32_bf16(qhi[1], kl1, accs[tt], 0, 0, 0);
      accs[tt] = __builtin_amdgcn_mfma_f32_16x16x32_bf16(qlo[0], kh0, accs[tt], 0, 0, 0);
      accs[tt] = __builtin_amdgcn_mfma_f32_16x16x32_bf16(qlo[1], kh1, accs[tt], 0, 0, 0);
    }
  }

  // ---- row max (rows 4g+r), cross-wave via LDS ----
  float vm[4];
#pragma unroll
  for (int r = 0; r < 4; ++r) {
    float m = accs[0][r];
#pragma unroll
    for (int tt = 1; tt < 32; ++tt) m = fmaxf(m, accs[tt][r]);
#pragma unroll
    for (int o = 1; o < 16; o <<= 1) m = fmaxf(m, __shfl_xor(m, o));
    vm[r] = m;
  }
  if (c == 0) {
#pragma unroll
    for (int r = 0; r < 4; ++r) vz[g * 4 + r][w] = vm[r];
  }
  __syncthreads();
#pragma unroll
  for (int r = 0; r < 4; ++r) {
    float4 vv = *(float4*)&vz[g * 4 + r][0];
    vm[r] = fmaxf(fmaxf(vv.x, vv.y), fmaxf(vv.z, vv.w));
  }

  // ---- exact top-1024 threshold: bisection on u32 keys ----
  unsigned lo_[4], hi_[4];
#pragma unroll
  for (int r = 0; r < 4; ++r) {
    unsigned u = __float_as_uint(vm[r]);
    unsigned km = (u & 0x80000000u) ? ~u : (u | 0x80000000u);
    lo_[r] = 0x00800000u;  // key(-FLT_MAX)
    hi_[r] = km + 1u;
  }
#pragma unroll 1
  for (int it = 0; it < 32; ++it) {
    unsigned midk[4];
    float midf[4];
    int cnt[4];
#pragma unroll
    for (int r = 0; r < 4; ++r) {
      midk[r] = lo_[r] + ((hi_[r] - lo_[r]) >> 1);
      unsigned mk = midk[r];
      unsigned uf = (mk & 0x80000000u) ? (mk & 0x7FFFFFFFu) : ~mk;
      midf[r] = __uint_as_float(uf);
      cnt[r] = 0;
    }
#pragma unroll
    for (int tt = 0; tt < 32; ++tt)
#pragma unroll
      for (int r = 0; r < 4; ++r) cnt[r] += (accs[tt][r] >= midf[r]) ? 1 : 0;
#pragma unroll
    for (int r = 0; r < 4; ++r)
#pragma unroll
      for (int o = 1; o < 16; o <<= 1) cnt[r] += __shfl_xor(cnt[r], o);
    if (c == 0) {
#pragma unroll
      for (int r = 0; r < 4; ++r) cntp[g * 4 + r][w] = cnt[r];
    }
    __syncthreads();
#pragma unroll
    for (int r = 0; r < 4; ++r) {
      int4 cc = *(int4*)&cntp[g * 4 + r][0];
      int tot = cc.x + cc.y + cc.z + cc.w;
      if (tot >= TOPKN) lo_[r] = midk[r]; else hi_[r] = midk[r];
    }
    __syncthreads();
  }

  // ---- exp + P(bf16) to LDS + Z ----
  float Tf[4], z[4];
#pragma unroll
  for (int r = 0; r < 4; ++r) {
    unsigned k = lo_[r];
    unsigned uf = (k & 0x80000000u) ? (k & 0x7FFFFFFFu) : ~k;
    Tf[r] = __uint_as_float(uf);
    z[r] = 0.f;
  }
#pragma unroll
  for (int tt = 0; tt < 32; ++tt)
#pragma unroll
    for (int r = 0; r < 4; ++r) {
      float s = accs[tt][r];
      float e = (s >= Tf[r]) ? exp2f((s - vm[r]) * 1.44269504f) : 0.f;
      z[r] += e;
      P[g * 4 + r][w * 512 + tt * 16 + c] = f2bf(e);
    }
#pragma unroll
  for (int r = 0; r < 4; ++r)
#pragma unroll
    for (int o = 1; o < 16; o <<= 1) z[r] += __shfl_xor(z[r], o);
  if (c == 0) {
#pragma unroll
    for (int r = 0; r < 4; ++r) vz[g * 4 + r][w] = z[r];
  }
  __syncthreads();
  float rinv[4];
#pragma unroll
  for (int r = 0; r < 4; ++r) {
    float4 zz = *(float4*)&vz[g * 4 + r][0];
    rinv[r] = 1.f / (zz.x + zz.y + zz.z + zz.w);
  }

  // ---- PV: wave w owns d-slice [w*16, w*16+16) over all k ----
  f32x4 oa = (f32x4){0.f, 0.f, 0.f, 0.f};
  {
    const unsigned short* vbase = Vt + ((size_t)bh * DH + w * 16 + c) * SEQ;
#pragma unroll
    for (int kt = 0; kt < 64; ++kt) {
      s16x8 pa = *(const s16x8*)&P[c][kt * 32 + g * 8];
      s16x8 vb = *(const s16x8*)(vbase + kt * 32 + g * 8);
      oa = __builtin_amdgcn_mfma_f32_16x16x32_bf16(pa, vb, oa, 0, 0, 0);
    }
  }
#pragma unroll
  for (int r = 0; r < 4; ++r)
    Ctx[(rowb + q0 + g * 4 + r) * DM + h * DH + w * 16 + c] = oa[r] * rinv[r];
}

extern "C" void kernel_launch(void* const* d_in, const int* in_sizes, int n_in,
                              void* d_out, int out_size, void* d_ws, size_t ws_size,
                              hipStream_t stream) {
  const float* q  = (const float*)d_in[0];
  const float* k  = (const float*)d_in[1];
  const float* v  = (const float*)d_in[2];
  const float* Wq = (const float*)d_in[3];
  const float* bq = (const float*)d_in[4];
  const float* Wk = (const float*)d_in[5];
  const float* bk = (const float*)d_in[6];
  const float* Wv = (const float*)d_in[7];
  const float* bv = (const float*)d_in[8];
  const float* Wo = (const float*)d_in[9];
  const float* bo = (const float*)d_in[10];
  float* out = (float*)d_out;

  char* ws = (char*)d_ws;
  unsigned* QHL        = (unsigned*)ws;                       // 16 MiB (u32 packed)
  unsigned short* Khi  = (unsigned short*)(ws + (16u << 20)); // 8 MiB
  unsigned short* Klo  = (unsigned short*)(ws + (24u << 20)); // 8 MiB
  unsigned short* Vt   = (unsigned short*)(ws + (32u << 20)); // 8 MiB
  float* Ctx = (float*)ws;  // aliases QHL: element-exclusive per WG, race-free

  dim3 gg(DM / 128, MROWS / 128);
  gemm_xwT<1><<<gg, 256, 0, stream>>>(q, Wq, bq, QHL, nullptr, MROWS, DM, DM);
  gemm_xwT<2><<<gg, 256, 0, stream>>>(k, Wk, bk, Khi, Klo, MROWS, DM, DM);
  gemm_xwT<3><<<gg, 256, 0, stream>>>(v, Wv, bv, Vt, nullptr, MROWS, DM, DM);
  attn_mfma<<<BATCH * NH * (SEQ / 16), 256, 0, stream>>>(QHL, Khi, Klo, Vt, Ctx);
  gemm_xwT<0><<<gg, 256, 0, stream>>>(Ctx, Wo, bo, out, nullptr, MROWS, DM, DM);
}

// Round 3
// 822.448 us; speedup vs baseline: 4.2117x; 1.6116x over previous
//
#include <hip/hip_runtime.h>
#include <math.h>

#define BATCH 2
#define SEQ 2048
#define DM 1024
#define NH 16
#define DH 64
#define TOPKN 1024
#define MROWS (BATCH * SEQ)  // 4096

typedef float f32x4 __attribute__((ext_vector_type(4)));
typedef short s16x8 __attribute__((ext_vector_type(8)));
typedef short s16x4 __attribute__((ext_vector_type(4)));

__device__ __forceinline__ unsigned short f2bf(float x) {
  unsigned u = __float_as_uint(x);
  return (unsigned short)((u + 0x7FFFu + ((u >> 16) & 1u)) >> 16);
}
__device__ __forceinline__ unsigned packHL(float x) {
  unsigned h = f2bf(x);
  float r = x - __uint_as_float(h << 16);
  unsigned l = f2bf(r);
  return h | (l << 16);
}

// ---------------- W pre-convert: f32 -> hi/lo bf16 slabs ----------------
__global__ __launch_bounds__(256) void convW(const float* __restrict__ W,
                                             unsigned short* __restrict__ Whi,
                                             unsigned short* __restrict__ Wlo) {
  int i = (blockIdx.x * 256 + threadIdx.x) * 4;
  float4 x = *(const float4*)&W[i];
  float xs[4] = {x.x, x.y, x.z, x.w};
  union { s16x4 v; unsigned short s[4]; } hu, lu;
#pragma unroll
  for (int e = 0; e < 4; ++e) {
    unsigned short hb = f2bf(xs[e]);
    hu.s[e] = hb;
    lu.s[e] = f2bf(xs[e] - __uint_as_float((unsigned)hb << 16));
  }
  *(s16x4*)&Whi[i] = hu.v;
  *(s16x4*)&Wlo[i] = lu.v;
}

// ---------------- MFMA GEMM: C[4096,1024] = A @ W^T + bias ----------------
// 3-term split-bf16: Ahi*Bhi + Ahi*Blo + Alo*Bhi.
// BM=128, BN=64, BK=64; 256 threads (4 waves, 2x2), wave-tile 64x32.
// ASRC: 0 = f32 A (truncate-hi/RNE-lo split), 1 = packed u32 (hi|lo<<16).
// MODE: 0 f32 out, 1 packed Q(*0.125), 2 Khi/Klo, 3 Vt transposed.
template <int ASRC, int MODE>
__global__ __launch_bounds__(256) void gemm_mfma(
    const void* __restrict__ Asrc, const unsigned short* __restrict__ Whi,
    const unsigned short* __restrict__ Wlo, const float* __restrict__ bias,
    void* __restrict__ out0, void* __restrict__ out1) {
  __shared__ unsigned short Ah[128][64], Al[128][64];
  __shared__ unsigned short Bh[64][64], Bl[64][64];

  const int f = blockIdx.x;              // 512 blocks
  const int xcd = f & 7, s = f >> 3;     // s in 0..63
  const int bm = xcd * 4 + (s >> 4);     // 0..31 ; XCD keeps 4 row-blocks (A L2 reuse)
  const int bn = s & 15;                 // 0..15
  const int m0g = bm * 128, n0g = bn * 64;
  const int t = threadIdx.x, w = t >> 6, lane = t & 63;
  const int g = lane >> 4, c = lane & 15;
  const int wm = w >> 1, wn = w & 1;

  f32x4 acc[4][2];
#pragma unroll
  for (int i = 0; i < 4; ++i)
#pragma unroll
    for (int j = 0; j < 2; ++j) acc[i][j] = (f32x4){0.f, 0.f, 0.f, 0.f};

#pragma unroll 1
  for (int k0 = 0; k0 < 1024; k0 += 64) {
    // ---- stage A (reg-staged, split to hi/lo, XOR-swizzled octets) ----
#pragma unroll
    for (int i = 0; i < 4; ++i) {
      int oid = t * 4 + i;               // 1024 octets of 8 elems
      int r = oid >> 3, j = oid & 7;
      union { s16x8 v; unsigned short sh[8]; } hu, lu;
      if (ASRC == 0) {
        const float* src = (const float*)Asrc + (size_t)(m0g + r) * 1024 + k0 + j * 8;
        float4 x0 = *(const float4*)src, x1 = *(const float4*)(src + 4);
        float xs[8] = {x0.x, x0.y, x0.z, x0.w, x1.x, x1.y, x1.z, x1.w};
#pragma unroll
        for (int e = 0; e < 8; ++e) {
          unsigned u = __float_as_uint(xs[e]);
          hu.sh[e] = (unsigned short)(u >> 16);          // truncate-hi (residual exact)
          lu.sh[e] = f2bf(xs[e] - __uint_as_float(u & 0xFFFF0000u));
        }
      } else {
        const unsigned* src = (const unsigned*)Asrc + (size_t)(m0g + r) * 1024 + k0 + j * 8;
        uint4 u0 = *(const uint4*)src, u1 = *(const uint4*)(src + 4);
        unsigned us[8] = {u0.x, u0.y, u0.z, u0.w, u1.x, u1.y, u1.z, u1.w};
#pragma unroll
        for (int e = 0; e < 8; ++e) {
          hu.sh[e] = (unsigned short)(us[e] & 0xFFFFu);
          lu.sh[e] = (unsigned short)(us[e] >> 16);
        }
      }
      int od = (j ^ (r & 7)) * 8;
      *(s16x8*)&Ah[r][od] = hu.v;
      *(s16x8*)&Al[r][od] = lu.v;
    }
    // ---- stage B (pre-converted bf16 hi/lo) ----
#pragma unroll
    for (int i = 0; i < 4; ++i) {
      int oid = t * 4 + i;               // 1024 octets: 512 hi + 512 lo
      int pl = oid >> 9, idx = oid & 511, r = idx >> 3, j = idx & 7;
      const unsigned short* src = (pl ? Wlo : Whi) + (size_t)(n0g + r) * 1024 + k0 + j * 8;
      uint4 d = *(const uint4*)src;
      int od = (j ^ (r & 7)) * 8;
      if (pl) *(uint4*)&Bl[r][od] = d; else *(uint4*)&Bh[r][od] = d;
    }
    __syncthreads();
    // ---- MFMA ----
#pragma unroll
    for (int k2 = 0; k2 < 2; ++k2) {
      s16x8 ah[4], al4[4], bh[2], bl[2];
      int ob = ((k2 * 4 + g) ^ (c & 7)) * 8;
#pragma unroll
      for (int i = 0; i < 4; ++i) {
        int r = wm * 64 + i * 16 + c;
        ah[i] = *(const s16x8*)&Ah[r][ob];
        al4[i] = *(const s16x8*)&Al[r][ob];
      }
#pragma unroll
      for (int j = 0; j < 2; ++j) {
        int r = wn * 32 + j * 16 + c;
        bh[j] = *(const s16x8*)&Bh[r][ob];
        bl[j] = *(const s16x8*)&Bl[r][ob];
      }
#pragma unroll
      for (int i = 0; i < 4; ++i)
#pragma unroll
        for (int j = 0; j < 2; ++j) {
          acc[i][j] = __builtin_amdgcn_mfma_f32_16x16x32_bf16(ah[i], bh[j], acc[i][j], 0, 0, 0);
          acc[i][j] = __builtin_amdgcn_mfma_f32_16x16x32_bf16(ah[i], bl[j], acc[i][j], 0, 0, 0);
          acc[i][j] = __builtin_amdgcn_mfma_f32_16x16x32_bf16(al4[i], bh[j], acc[i][j], 0, 0, 0);
        }
    }
    __syncthreads();
  }

  // ---- epilogue: C row = m0g+wm*64+i*16+g*4+rr, col = n0g+wn*32+j*16+c ----
#pragma unroll
  for (int j = 0; j < 2; ++j) {
    const int col = n0g + wn * 32 + j * 16 + c;
    const float bj = bias[col];
#pragma unroll
    for (int i = 0; i < 4; ++i) {
      const int row0 = m0g + wm * 64 + i * 16 + g * 4;
      if (MODE == 0) {
        float* O = (float*)out0;
#pragma unroll
        for (int rr = 0; rr < 4; ++rr)
          O[(size_t)(row0 + rr) * 1024 + col] = acc[i][j][rr] + bj;
      } else if (MODE == 1) {
        unsigned* Q = (unsigned*)out0;
#pragma unroll
        for (int rr = 0; rr < 4; ++rr)
          Q[(size_t)(row0 + rr) * 1024 + col] = packHL((acc[i][j][rr] + bj) * 0.125f);
      } else if (MODE == 2) {
        unsigned short* Khi = (unsigned short*)out0;
        unsigned short* Klo = (unsigned short*)out1;
#pragma unroll
        for (int rr = 0; rr < 4; ++rr) {
          float x = acc[i][j][rr] + bj;
          unsigned short hb = f2bf(x);
          Khi[(size_t)(row0 + rr) * 1024 + col] = hb;
          Klo[(size_t)(row0 + rr) * 1024 + col] = f2bf(x - __uint_as_float((unsigned)hb << 16));
        }
      } else {  // MODE 3: Vt[b][h][dh][l], 4 consecutive l per lane
        unsigned short* Vt = (unsigned short*)out0;
        int b = row0 >> 11, l0 = row0 & (SEQ - 1);
        int h = col >> 6, dh = col & 63;
        union { s16x4 v; unsigned short sh[4]; } vv;
#pragma unroll
        for (int rr = 0; rr < 4; ++rr) vv.sh[rr] = f2bf(acc[i][j][rr] + bj);
        *(s16x4*)&Vt[(((size_t)b * NH + h) * DH + dh) * SEQ + l0] = vv.v;
      }
    }
  }
}

// ---------------- fused prob-sparse attention (MFMA) ----------------
__global__ __launch_bounds__(256, 2) void attn_mfma(
    const unsigned* __restrict__ QHL, const unsigned short* __restrict__ Khi,
    const unsigned short* __restrict__ Klo, const unsigned short* __restrict__ Vt,
    unsigned* __restrict__ CtxP) {
  __shared__ unsigned short P[16][2056];            // 65792 B
  __shared__ __align__(16) float vz[16][4];         // max partials, then Z partials
  __shared__ __align__(16) float vnl[16][4];        // min partials
  __shared__ unsigned cnt2[2][4][4][2];             // [parity][wave][g][rowpair]

  int wg = blockIdx.x;
  wg = (wg & 7) * 512 + (wg >> 3);                  // XCD-contiguous (b,h) groups
  const int bh = wg >> 7, qt = wg & 127;
  const int b = bh >> 4, h = bh & 15;
  const int q0 = qt * 16;
  const int t = threadIdx.x, w = t >> 6, lane = t & 63;
  const int g = lane >> 4, c = lane & 15;
  const size_t rowb = (size_t)b * SEQ;

  // ---- Q fragments (packed u32, pre-scaled by 1/8) ----
  s16x8 qhi[2], qlo[2];
  {
    const unsigned* qp = QHL + (rowb + q0 + c) * DM + h * DH + g * 8;
#pragma unroll
    for (int ds = 0; ds < 2; ++ds) {
      unsigned uw[8];
      *(uint4*)&uw[0] = *(const uint4*)(qp + ds * 32);
      *(uint4*)&uw[4] = *(const uint4*)(qp + ds * 32 + 4);
      union { s16x8 v; unsigned u[4]; } hi_, lo_;
#pragma unroll
      for (int p = 0; p < 4; ++p) {
        hi_.u[p] = (uw[2 * p] & 0xFFFFu) | (uw[2 * p + 1] << 16);
        lo_.u[p] = (uw[2 * p] >> 16) | (uw[2 * p + 1] & 0xFFFF0000u);
      }
      qhi[ds] = hi_.v; qlo[ds] = lo_.v;
    }
  }

  // ---- QK^T: S = Qhi*Khi + Qhi*Klo + Qlo*Khi ----
  f32x4 accs[32];
#pragma unroll
  for (int i = 0; i < 32; ++i) accs[i] = (f32x4){0.f, 0.f, 0.f, 0.f};
  {
    const size_t kcol = (size_t)h * DH + g * 8;
#pragma unroll
    for (int tt = 0; tt < 32; ++tt) {
      const size_t krow = (rowb + w * 512 + tt * 16 + c) * DM + kcol;
      s16x8 kh0 = *(const s16x8*)(Khi + krow);
      s16x8 kh1 = *(const s16x8*)(Khi + krow + 32);
      s16x8 kl0 = *(const s16x8*)(Klo + krow);
      s16x8 kl1 = *(const s16x8*)(Klo + krow + 32);
      accs[tt] = __builtin_amdgcn_mfma_f32_16x16x32_bf16(qhi[0], kh0, accs[tt], 0, 0, 0);
      accs[tt] = __builtin_amdgcn_mfma_f32_16x16x32_bf16(qhi[1], kh1, accs[tt], 0, 0, 0);
      accs[tt] = __builtin_amdgcn_mfma_f32_16x16x32_bf16(qhi[0], kl0, accs[tt], 0, 0, 0);
      accs[tt] = __builtin_amdgcn_mfma_f32_16x16x32_bf16(qhi[1], kl1, accs[tt], 0, 0, 0);
      accs[tt] = __builtin_amdgcn_mfma_f32_16x16x32_bf16(qlo[0], kh0, accs[tt], 0, 0, 0);
      accs[tt] = __builtin_amdgcn_mfma_f32_16x16x32_bf16(qlo[1], kh1, accs[tt], 0, 0, 0);
    }
  }

  // ---- row max & min, cross-wave via LDS (one barrier) ----
  float vm[4], vn_[4];
#pragma unroll
  for (int r = 0; r < 4; ++r) {
    float m = accs[0][r], n = accs[0][r];
#pragma unroll
    for (int tt = 1; tt < 32; ++tt) {
      m = fmaxf(m, accs[tt][r]);
      n = fminf(n, accs[tt][r]);
    }
#pragma unroll
    for (int o = 1; o < 16; o <<= 1) {
      m = fmaxf(m, __shfl_xor(m, o));
      n = fminf(n, __shfl_xor(n, o));
    }
    vm[r] = m; vn_[r] = n;
  }
  if (c == 0) {
#pragma unroll
    for (int r = 0; r < 4; ++r) { vz[g * 4 + r][w] = vm[r]; vnl[g * 4 + r][w] = vn_[r]; }
  }
  __syncthreads();
#pragma unroll
  for (int r = 0; r < 4; ++r) {
    float4 a = *(float4*)&vz[g * 4 + r][0];
    float4 d = *(float4*)&vnl[g * 4 + r][0];
    vm[r] = fmaxf(fmaxf(a.x, a.y), fmaxf(a.z, a.w));
    vn_[r] = fminf(fminf(d.x, d.y), fminf(d.z, d.w));
  }

  // ---- top-1024 threshold: float bisection, 1 barrier/iter ----
  float blo[4], bhi[4];
#pragma unroll
  for (int r = 0; r < 4; ++r) { blo[r] = vn_[r]; bhi[r] = vm[r]; }
#pragma unroll 1
  for (int it = 0; it < 23; ++it) {
    const int par = it & 1;
    float mid[4];
    int cnt[4];
#pragma unroll
    for (int r = 0; r < 4; ++r) {
      mid[r] = 0.5f * (blo[r] + bhi[r]);
      cnt[r] = 0;
    }
#pragma unroll
    for (int tt = 0; tt < 32; ++tt)
#pragma unroll
      for (int r = 0; r < 4; ++r) cnt[r] += (accs[tt][r] >= mid[r]) ? 1 : 0;
    unsigned p0 = (unsigned)cnt[0] | ((unsigned)cnt[1] << 16);
    unsigned p1 = (unsigned)cnt[2] | ((unsigned)cnt[3] << 16);
#pragma unroll
    for (int o = 1; o < 16; o <<= 1) {
      p0 += __shfl_xor(p0, o);
      p1 += __shfl_xor(p1, o);
    }
    if (c == 0) { cnt2[par][w][g][0] = p0; cnt2[par][w][g][1] = p1; }
    __syncthreads();
    unsigned s0 = cnt2[par][0][g][0] + cnt2[par][1][g][0] + cnt2[par][2][g][0] + cnt2[par][3][g][0];
    unsigned s1 = cnt2[par][0][g][1] + cnt2[par][1][g][1] + cnt2[par][2][g][1] + cnt2[par][3][g][1];
    int tot[4] = {(int)(s0 & 0xFFFFu), (int)(s0 >> 16), (int)(s1 & 0xFFFFu), (int)(s1 >> 16)};
#pragma unroll
    for (int r = 0; r < 4; ++r) {
      bool ge = tot[r] >= TOPKN;
      blo[r] = ge ? mid[r] : blo[r];
      bhi[r] = ge ? bhi[r] : mid[r];
    }
  }

  // ---- exp + P(bf16) to LDS + Z ----
  float z[4];
#pragma unroll
  for (int r = 0; r < 4; ++r) z[r] = 0.f;
#pragma unroll
  for (int tt = 0; tt < 32; ++tt)
#pragma unroll
    for (int r = 0; r < 4; ++r) {
      float s = accs[tt][r];
      float e = (s >= blo[r]) ? exp2f((s - vm[r]) * 1.44269504f) : 0.f;
      z[r] += e;
      P[g * 4 + r][w * 512 + tt * 16 + c] = f2bf(e);
    }
#pragma unroll
  for (int r = 0; r < 4; ++r)
#pragma unroll
    for (int o = 1; o < 16; o <<= 1) z[r] += __shfl_xor(z[r], o);
  if (c == 0) {
#pragma unroll
    for (int r = 0; r < 4; ++r) vz[g * 4 + r][w] = z[r];
  }
  __syncthreads();
  float rinv[4];
#pragma unroll
  for (int r = 0; r < 4; ++r) {
    float4 zz = *(float4*)&vz[g * 4 + r][0];
    rinv[r] = 1.f / (zz.x + zz.y + zz.z + zz.w);
  }

  // ---- PV: wave w owns d-slice [w*16, w*16+16) over all k ----
  f32x4 oa = (f32x4){0.f, 0.f, 0.f, 0.f};
  {
    const unsigned short* vbase = Vt + ((size_t)bh * DH + w * 16 + c) * SEQ;
#pragma unroll
    for (int kt = 0; kt < 64; ++kt) {
      s16x8 pa = *(const s16x8*)&P[c][kt * 32 + g * 8];
      s16x8 vb = *(const s16x8*)(vbase + kt * 32 + g * 8);
      oa = __builtin_amdgcn_mfma_f32_16x16x32_bf16(pa, vb, oa, 0, 0, 0);
    }
  }
#pragma unroll
  for (int r = 0; r < 4; ++r)
    CtxP[(rowb + q0 + g * 4 + r) * DM + h * DH + w * 16 + c] = packHL(oa[r] * rinv[r]);
}

extern "C" void kernel_launch(void* const* d_in, const int* in_sizes, int n_in,
                              void* d_out, int out_size, void* d_ws, size_t ws_size,
                              hipStream_t stream) {
  const float* q  = (const float*)d_in[0];
  const float* k  = (const float*)d_in[1];
  const float* v  = (const float*)d_in[2];
  const float* Wq = (const float*)d_in[3];
  const float* bq = (const float*)d_in[4];
  const float* Wk = (const float*)d_in[5];
  const float* bk = (const float*)d_in[6];
  const float* Wv = (const float*)d_in[7];
  const float* bv = (const float*)d_in[8];
  const float* Wo = (const float*)d_in[9];
  const float* bo = (const float*)d_in[10];
  float* out = (float*)d_out;

  char* ws = (char*)d_ws;
  unsigned* QHL       = (unsigned*)ws;                        // 16 MiB (packed hi|lo)
  unsigned short* Khi = (unsigned short*)(ws + (16u << 20));  // 8 MiB
  unsigned short* Klo = (unsigned short*)(ws + (24u << 20));  // 8 MiB
  unsigned short* Vt  = (unsigned short*)(ws + (32u << 20));  // 8 MiB
  unsigned short* Whi = (unsigned short*)(ws + (40u << 20));  // 2 MiB (reused)
  unsigned short* Wlo = (unsigned short*)(ws + (42u << 20));  // 2 MiB (reused)

  convW<<<1024, 256, 0, stream>>>(Wq, Whi, Wlo);
  gemm_mfma<0, 1><<<512, 256, 0, stream>>>(q, Whi, Wlo, bq, QHL, nullptr);
  convW<<<1024, 256, 0, stream>>>(Wk, Whi, Wlo);
  gemm_mfma<0, 2><<<512, 256, 0, stream>>>(k, Whi, Wlo, bk, Khi, Klo);
  convW<<<1024, 256, 0, stream>>>(Wv, Whi, Wlo);
  gemm_mfma<0, 3><<<512, 256, 0, stream>>>(v, Whi, Wlo, bv, Vt, nullptr);
  attn_mfma<<<BATCH * NH * (SEQ / 16), 256, 0, stream>>>(QHL, Khi, Klo, Vt, QHL);
  convW<<<1024, 256, 0, stream>>>(Wo, Whi, Wlo);
  gemm_mfma<1, 0><<<512, 256, 0, stream>>>(QHL, Whi, Wlo, bo, out, nullptr);
}